// Round 1
// baseline (114.435 us; speedup 1.0000x reference)
//
#include <hip/hip_runtime.h>
#include <hip/hip_bf16.h>

typedef unsigned int u32;
typedef unsigned short u16;

#define BATCH 256
#define NN 4096
#define DIM 512

__device__ inline float b2f(u16 u){ u32 i = ((u32)u)<<16; float f; __builtin_memcpy(&f,&i,4); return f; }

__device__ inline float ldv(const void* p, size_t i, int isbf){
  return isbf ? b2f(((const u16*)p)[i]) : ((const float*)p)[i];
}
__device__ inline void stv(void* p, size_t i, float v, int isbf){
  if (isbf) ((__hip_bfloat16*)p)[i] = __float2bfloat16(v);
  else ((float*)p)[i] = v;
}
// load 8 consecutive elements (idx must be multiple of 8)
__device__ inline void load8(const void* p, size_t idx, int isbf, float* o){
  if (isbf){
    uint4 v = *(const uint4*)((const u16*)p + idx);
    u32 a[4] = {v.x, v.y, v.z, v.w};
    #pragma unroll
    for (int q=0;q<4;q++){ o[2*q] = b2f((u16)(a[q]&0xffffu)); o[2*q+1] = b2f((u16)(a[q]>>16)); }
  } else {
    const float* f = (const float*)p + idx;
    float4 va = *(const float4*)f;
    float4 vb = *(const float4*)(f+4);
    o[0]=va.x;o[1]=va.y;o[2]=va.z;o[3]=va.w;o[4]=vb.x;o[5]=vb.y;o[6]=vb.z;o[7]=vb.w;
  }
}

// K0: decide whether float buffers are bf16 (harness-converted) or f32.
// Low 16 bits of each 32-bit word: for a true bf16 array these are real bf16
// values (sane exponents); for f32 they are mantissa noise (~10% sane).
__global__ void k_sniff(const void* X, int* flag){
  int t = threadIdx.x; // 64 threads, one wave
  u32 v = ((const u32*)X)[t];
  u16 lo = (u16)(v & 0xffffu);
  int e = (lo >> 7) & 0xff;
  int sane = ((lo & 0x7fffu) == 0) || (e >= 110 && e <= 132);
  unsigned long long m = __ballot(sane);
  if (t == 0) *flag = (__popcll(m) >= 32) ? 1 : 0;
}

// K1: w2[n] = sum_d pesos[n,d]^2 ; one wave per row
__global__ __launch_bounds__(256) void k_w2(const void* W, const int* flag, float* w2){
  int t = threadIdx.x; int wv = t>>6, lane = t&63;
  int n = blockIdx.x*4 + wv;
  int isbf = *flag;
  float x[8]; load8(W, (size_t)n*DIM + lane*8, isbf, x);
  float s = 0.f;
  #pragma unroll
  for (int j=0;j<8;j++) s += x[j]*x[j];
  #pragma unroll
  for (int off=32; off; off>>=1) s += __shfl_down(s, off);
  if (lane == 0) w2[n] = s;
}

// K2: score[b,n] = w2[n] - 2*dot(X[b], W[n]); partial argmin per (b, n-chunk).
// grid (4 n-chunks of 1024, 32 b-tiles of 8); thread: 4 n (stride 256) x 8 b.
__global__ __launch_bounds__(256) void k_score(const void* X, const void* W, const float* w2,
                                               const int* flag, float* pval, int* pidx){
  __shared__ __align__(16) float xs[8][DIM];
  __shared__ float cval[8][4];
  __shared__ int   cidx[8][4];
  int t = threadIdx.x;
  int c = blockIdx.x, bt = blockIdx.y;
  int isbf = *flag;
  int b0 = bt*8;
  for (int i=t; i<8*DIM; i+=256){
    int bb = i>>9, k = i&511;
    size_t gi = (size_t)(b0+bb)*DIM + k;
    xs[bb][k] = isbf ? b2f(((const u16*)X)[gi]) : ((const float*)X)[gi];
  }
  __syncthreads();

  int n[4];
  #pragma unroll
  for (int i=0;i<4;i++) n[i] = c*1024 + i*256 + t;
  float acc[4][8];
  #pragma unroll
  for (int i=0;i<4;i++)
    #pragma unroll
    for (int bb=0;bb<8;bb++) acc[i][bb] = 0.f;

  for (int k8=0;k8<DIM/8;k8++){
    float w[4][8];
    #pragma unroll
    for (int i=0;i<4;i++) load8(W, (size_t)n[i]*DIM + k8*8, isbf, w[i]);
    #pragma unroll
    for (int bb=0;bb<8;bb++){
      float4 xa = *(const float4*)&xs[bb][k8*8];
      float4 xb = *(const float4*)&xs[bb][k8*8+4];
      float x[8] = {xa.x,xa.y,xa.z,xa.w,xb.x,xb.y,xb.z,xb.w};
      #pragma unroll
      for (int j=0;j<8;j++){
        #pragma unroll
        for (int i=0;i<4;i++) acc[i][bb] += x[j]*w[i][j];
      }
    }
  }

  float w2v[4];
  #pragma unroll
  for (int i=0;i<4;i++) w2v[i] = w2[n[i]];

  int lane = t&63, wv = t>>6;
  #pragma unroll 1
  for (int bb=0;bb<8;bb++){
    float v = w2v[0] - 2.f*acc[0][bb]; int ix = n[0];
    #pragma unroll
    for (int i=1;i<4;i++){
      float vi = w2v[i] - 2.f*acc[i][bb];
      if (vi < v || (vi == v && n[i] < ix)){ v = vi; ix = n[i]; }
    }
    for (int off=32; off; off>>=1){
      float ov = __shfl_down(v, off);
      int   oi = __shfl_down(ix, off);
      if (ov < v || (ov == v && oi < ix)){ v = ov; ix = oi; }
    }
    if (lane == 0){ cval[bb][wv] = v; cidx[bb][wv] = ix; }
  }
  __syncthreads();
  if (t < 8){
    float v = cval[t][0]; int ix = cidx[t][0];
    #pragma unroll
    for (int w4=1;w4<4;w4++){
      float ov = cval[t][w4]; int oi = cidx[t][w4];
      if (ov < v || (ov == v && oi < ix)){ v = ov; ix = oi; }
    }
    pval[(size_t)(b0+t)*4 + c] = v;
    pidx[(size_t)(b0+t)*4 + c] = ix;
  }
}

// K3: final argmin across 4 chunks per b; also write taxa/sigma scalars.
__global__ void k_final(const float* pval, const int* pidx, int* bmu, const int* flag,
                        const int* passo, const int* total, void* out){
  int t = threadIdx.x; // 256 threads, t = b
  float v = pval[t*4]; int ix = pidx[t*4];
  #pragma unroll
  for (int c=1;c<4;c++){
    float ov = pval[t*4+c]; int oi = pidx[t*4+c];
    if (ov < v || (ov == v && oi < ix)){ v = ov; ix = oi; }
  }
  bmu[t] = ix;
  if (t == 0){
    float decay = expf(-(float)passo[0] / (float)total[0]);
    float taxa = 0.5f * decay;
    float sigma = 32.0f * decay;
    int isbf = *flag;
    stv(out, (size_t)NN*DIM,     taxa,  isbf);
    stv(out, (size_t)NN*DIM + 1, sigma, isbf);
  }
}

// K4: out[n,d] = W[n,d] + (taxa/B)*(sum_b h[b,n]X[b,d] - hsum[n]*W[n,d])
// h recomputed from bmu. Block: 8 n rows, thread: 2 d columns.
__global__ __launch_bounds__(256) void k_update(const void* X, const void* W, const int* bmu,
                                                const int* flag, const int* passo, const int* total,
                                                void* out){
  __shared__ __align__(16) float hl[8][BATCH];
  __shared__ float hsum[8];
  int t = threadIdx.x;
  int n0 = blockIdx.x*8;
  int isbf = *flag;
  float decay = expf(-(float)passo[0] / (float)total[0]);
  float taxa = 0.5f * decay;
  float sigma = 32.0f * decay;
  float inv2s2 = 1.0f / (2.0f * sigma * sigma);

  { // h[b, n0+i] for b = t
    int m = bmu[t];
    int mx = m & 63, my = m >> 6;
    #pragma unroll
    for (int i=0;i<8;i++){
      int n = n0 + i;
      int dx = (n & 63) - mx;
      int dy = (n >> 6) - my;
      float d2 = (float)(dx*dx + dy*dy);
      hl[i][t] = expf(-d2 * inv2s2);
    }
  }
  __syncthreads();
  { // row sums: wave wv handles rows wv and wv+4
    int wv = t>>6, lane = t&63;
    #pragma unroll
    for (int rr=0; rr<2; rr++){
      int r = wv + rr*4;
      float s = hl[r][lane] + hl[r][lane+64] + hl[r][lane+128] + hl[r][lane+192];
      #pragma unroll
      for (int off=32; off; off>>=1) s += __shfl_down(s, off);
      if (lane == 0) hsum[r] = s;
    }
  }
  __syncthreads();

  int d0 = t*2;
  float acc[8][2];
  #pragma unroll
  for (int i=0;i<8;i++){ acc[i][0]=0.f; acc[i][1]=0.f; }

  for (int b=0;b<BATCH;b+=4){
    float4 hv[8];
    #pragma unroll
    for (int i=0;i<8;i++) hv[i] = *(const float4*)&hl[i][b];
    #pragma unroll
    for (int bb=0;bb<4;bb++){
      float x0, x1;
      size_t gi = (size_t)(b+bb)*DIM + d0;
      if (isbf){
        u32 v = *(const u32*)((const u16*)X + gi);
        x0 = b2f((u16)(v & 0xffffu)); x1 = b2f((u16)(v >> 16));
      } else {
        float2 f = *(const float2*)((const float*)X + gi);
        x0 = f.x; x1 = f.y;
      }
      #pragma unroll
      for (int i=0;i<8;i++){
        float h = ((const float*)&hv[i])[bb];
        acc[i][0] += h*x0;
        acc[i][1] += h*x1;
      }
    }
  }

  float cc = taxa / (float)BATCH;
  #pragma unroll
  for (int i=0;i<8;i++){
    int n = n0 + i;
    float hs = hsum[i];
    #pragma unroll
    for (int j=0;j<2;j++){
      size_t gi = (size_t)n*DIM + d0 + j;
      float wv = ldv(W, gi, isbf);
      float o = wv + cc*(acc[i][j] - hs*wv);
      stv(out, gi, o, isbf);
    }
  }
}

extern "C" void kernel_launch(void* const* d_in, const int* in_sizes, int n_in,
                              void* d_out, int out_size, void* d_ws, size_t ws_size,
                              hipStream_t stream) {
  const void* X = d_in[0];      // (256, 512)
  const void* W = d_in[1];      // (4096, 512)
  // d_in[2] = localizacoes — recomputed on device as (n%64, n/64)
  const int* passo = (const int*)d_in[3];
  const int* total = (const int*)d_in[4];

  char* ws = (char*)d_ws;
  int*   flag = (int*)(ws + 0);
  float* w2   = (float*)(ws + 256);
  float* pval = (float*)(ws + 256 + 16384);          // 256*4 floats
  int*   pidx = (int*)  (ws + 256 + 16384 + 4096);   // 256*4 ints
  int*   bmu  = (int*)  (ws + 256 + 16384 + 8192);   // 256 ints

  k_sniff<<<1, 64, 0, stream>>>(X, flag);
  k_w2<<<NN/4, 256, 0, stream>>>(W, flag, w2);
  k_score<<<dim3(4, 32), 256, 0, stream>>>(X, W, w2, flag, pval, pidx);
  k_final<<<1, 256, 0, stream>>>(pval, pidx, bmu, flag, passo, total, d_out);
  k_update<<<NN/8, 256, 0, stream>>>(X, W, bmu, flag, passo, total, d_out);
}

// Round 2
// 55.360 us; speedup vs baseline: 2.0671x; 2.0671x over previous
//
#include <hip/hip_runtime.h>
#include <hip/hip_bf16.h>

typedef unsigned int u32;
typedef unsigned short u16;
typedef unsigned long long u64;

#define BATCH 256
#define NN 4096
#define DIM 512

using short8 = __attribute__((ext_vector_type(8))) short;
using f32x4  = __attribute__((ext_vector_type(4))) float;

__device__ inline float b2f(u16 u){ u32 i = ((u32)u)<<16; float f; __builtin_memcpy(&f,&i,4); return f; }
__device__ inline u16 f2b(float v){ __hip_bfloat16 h = __float2bfloat16(v); u16 r; __builtin_memcpy(&r,&h,2); return r; }

__device__ inline float ldv(const void* p, size_t i, int isbf){
  return isbf ? b2f(((const u16*)p)[i]) : ((const float*)p)[i];
}
__device__ inline void stv(void* p, size_t i, float v, int isbf){
  if (isbf) ((__hip_bfloat16*)p)[i] = __float2bfloat16(v);
  else ((float*)p)[i] = v;
}

// K0: sniff dtype, init pack buffer, write taxa/sigma scalars.
__global__ void k_prep(const void* X, int* flag, u64* pack,
                       const int* passo, const int* total, void* out){
  __shared__ int sflag;
  int t = threadIdx.x; // 256
  if (t < 64){
    u32 v = ((const u32*)X)[t];
    u16 lo = (u16)(v & 0xffffu);
    int e = (lo >> 7) & 0xff;
    int sane = ((lo & 0x7fffu) == 0) || (e >= 110 && e <= 132);
    u64 m = __ballot(sane);
    if (t == 0){ int f = (__popcll(m) >= 32) ? 1 : 0; sflag = f; *flag = f; }
  }
  pack[t] = ~0ull;
  __syncthreads();
  if (t == 0){
    float decay = expf(-(float)passo[0] / (float)total[0]);
    stv(out, (size_t)NN*DIM,     0.5f*decay, sflag);
    stv(out, (size_t)NN*DIM + 1, 32.f*decay, sflag);
  }
}

// K1: build XT[d][b] (bf16, always) + convert X,W to bf16 ws copies if f32.
__global__ __launch_bounds__(256) void k_stage(const void* X, const void* W, const int* flag,
                                               u16* XT, u16* Xb, u16* Wb){
  int isbf = *flag;
  int b = blockIdx.x, t = threadIdx.x;   // 512 blocks: d = b
  float v = ldv(X, (size_t)t*DIM + b, isbf);
  XT[(size_t)b*BATCH + t] = f2b(v);
  if (!isbf){
    size_t i = (size_t)b*256 + t;        // 512*256 = 131072 = |X|
    Xb[i] = f2b(((const float*)X)[i]);
    #pragma unroll
    for (int it=0; it<16; ++it){         // 512*4096 = 2M = |W|
      size_t j = (size_t)b*4096 + (size_t)it*256 + t;
      Wb[j] = f2b(((const float*)W)[j]);
    }
  }
}

// K2: w2[n] = ||W[n]||^2, one wave per row.
__global__ __launch_bounds__(256) void k_w2(const void* W, const u16* Wws, const int* flag, float* w2){
  int t = threadIdx.x; int wv = t>>6, lane = t&63;
  const u16* Wb = (*flag) ? (const u16*)W : Wws;
  int n = blockIdx.x*4 + wv;
  short8 x = *(const short8*)(Wb + (size_t)n*DIM + lane*8);
  float s = 0.f;
  #pragma unroll
  for (int j=0;j<8;j++){ float f = b2f((u16)x[j]); s += f*f; }
  #pragma unroll
  for (int off=32; off; off>>=1) s += __shfl_down(s, off);
  if (lane == 0) w2[n] = s;
}

// K3: MFMA score + fused argmin via packed atomicMin.
// Wave tile: 16 b x 32 n. Block: 4 waves (128 n). Grid (16 b-tiles, 32 n-chunks).
__global__ __launch_bounds__(256) void k_score(const void* X, const void* W,
                                               const u16* Xws, const u16* Wws,
                                               const int* flag, const float* w2, u64* pack){
  int isbf = *flag;
  const u16* Xb = isbf ? (const u16*)X : Xws;
  const u16* Wb = isbf ? (const u16*)W : Wws;
  int t = threadIdx.x;
  int wv = t>>6, l = t&63;
  int lr = l & 15, lg = l >> 4;
  int b0 = blockIdx.x * 16;
  int n0 = blockIdx.y * 128 + wv * 32;

  const u16* xp = Xb + (size_t)(b0 + lr)*DIM + lg*8;
  const u16* wp = Wb + (size_t)(n0 + lr)*DIM + lg*8;

  f32x4 acc0 = {0.f,0.f,0.f,0.f};
  f32x4 acc1 = {0.f,0.f,0.f,0.f};
  #pragma unroll
  for (int ks=0; ks<16; ++ks){
    short8 a  = *(const short8*)(xp + ks*32);
    short8 bA = *(const short8*)(wp + ks*32);
    short8 bB = *(const short8*)(wp + (size_t)16*DIM + ks*32);
    acc0 = __builtin_amdgcn_mfma_f32_16x16x32_bf16(a, bA, acc0, 0,0,0);
    acc1 = __builtin_amdgcn_mfma_f32_16x16x32_bf16(a, bB, acc1, 0,0,0);
  }

  float w20 = w2[n0 + lr];
  float w21 = w2[n0 + 16 + lr];
  #pragma unroll
  for (int r=0;r<4;++r){
    float s0 = w20 - 2.f*acc0[r];
    float s1 = w21 - 2.f*acc1[r];
    float bv; int bi;
    if (s0 <= s1){ bv = s0; bi = n0 + lr; } else { bv = s1; bi = n0 + 16 + lr; }
    #pragma unroll
    for (int m=1; m<16; m<<=1){
      float ov = __shfl_xor(bv, m);
      int   oi = __shfl_xor(bi, m);
      if (ov < bv || (ov == bv && oi < bi)){ bv = ov; bi = oi; }
    }
    if (lr == 0){
      int b = b0 + lg*4 + r;
      u32 sb = __float_as_uint(bv);
      sb = (sb & 0x80000000u) ? ~sb : (sb | 0x80000000u);
      u64 key = ((u64)sb << 32) | (u32)bi;
      atomicMin(pack + b, key);
    }
  }
}

// K4: h tile in LDS -> MFMA hX = h @ XT -> fused SOM update.
// Block: 16 n rows, 512 threads = 8 waves, wave wv covers d in [wv*64, wv*64+64).
__global__ __launch_bounds__(512) void k_update(const u16* XT, const void* W, const u64* pack,
                                                const int* flag, const int* passo, const int* total,
                                                void* out){
  __shared__ u16 hT[16][264];   // pad: row stride 132 dwords -> even 8-slot bank spread
  __shared__ float hpart[8][8];
  __shared__ float hs[16];
  int t = threadIdx.x;
  int wv = t>>6, l = t&63;
  int n0 = blockIdx.x * 16;
  int isbf = *flag;

  float decay = expf(-(float)passo[0] / (float)total[0]);
  float taxa = 0.5f*decay, sigma = 32.f*decay;
  float inv2s2 = 1.f/(2.f*sigma*sigma);

  { // fill h: thread handles b = t&255, rows base (t>>8)*8 .. +8
    int b = t & 255;
    int rbase = (t >> 8) * 8;
    int m = (int)(u32)(pack[b] & 0xffffffffu);
    int mx = m & 63, my = m >> 6;
    float hv[8];
    #pragma unroll
    for (int i=0;i<8;++i){
      int n = n0 + rbase + i;
      int dx = (n & 63) - mx;
      int dy = (n >> 6) - my;
      float h = expf(-(float)(dx*dx + dy*dy) * inv2s2);
      hv[i] = h;
      hT[rbase + i][b] = f2b(h);
    }
    #pragma unroll
    for (int i=0;i<8;++i){
      float s = hv[i];
      #pragma unroll
      for (int off=32; off; off>>=1) s += __shfl_down(s, off);
      if (l == 0) hpart[wv][i] = s;
    }
  }
  __syncthreads();
  if (t < 16){
    int g = (t >> 3) * 4;
    hs[t] = hpart[g][t&7] + hpart[g+1][t&7] + hpart[g+2][t&7] + hpart[g+3][t&7];
  }
  __syncthreads();

  int lr = l & 15, lg = l >> 4;
  int d0 = wv * 64;
  f32x4 acc[4];
  #pragma unroll
  for (int f=0;f<4;++f) acc[f] = (f32x4){0.f,0.f,0.f,0.f};

  #pragma unroll
  for (int ks=0; ks<8; ++ks){
    short8 a = *(const short8*)(&hT[lr][ks*32 + lg*8]);
    #pragma unroll
    for (int f=0; f<4; ++f){
      short8 bfr = *(const short8*)(XT + (size_t)(d0 + f*16 + lr)*BATCH + ks*32 + lg*8);
      acc[f] = __builtin_amdgcn_mfma_f32_16x16x32_bf16(a, bfr, acc[f], 0,0,0);
    }
  }

  float cc = taxa / (float)BATCH;
  #pragma unroll
  for (int r=0;r<4;++r){
    int n = n0 + lg*4 + r;
    float hsv = hs[lg*4 + r];
    #pragma unroll
    for (int f=0;f<4;++f){
      size_t gi = (size_t)n*DIM + d0 + f*16 + lr;
      float wv_ = ldv(W, gi, isbf);
      float o = wv_ + cc*(acc[f][r] - hsv*wv_);
      stv(out, gi, o, isbf);
    }
  }
}

extern "C" void kernel_launch(void* const* d_in, const int* in_sizes, int n_in,
                              void* d_out, int out_size, void* d_ws, size_t ws_size,
                              hipStream_t stream) {
  const void* X = d_in[0];      // (256, 512)
  const void* W = d_in[1];      // (4096, 512)
  // d_in[2] = localizacoes — recomputed on device as (n%64, n/64)
  const int* passo = (const int*)d_in[3];
  const int* total = (const int*)d_in[4];

  char* ws = (char*)d_ws;
  int* flag = (int*)(ws + 0);
  u64* pack = (u64*)(ws + 256);                 // 256 * 8 = 2048
  float* w2 = (float*)(ws + 2304);              // 4096 * 4 = 16384
  u16* XT   = (u16*)(ws + 18688);               // 512*256*2 = 262144
  u16* Xb   = (u16*)(ws + 280832);              // 131072*2 = 262144 (f32 fallback)
  u16* Wb   = (u16*)(ws + 542976);              // 2M*2 = 4 MiB (f32 fallback)

  k_prep <<<1, 256, 0, stream>>>(X, flag, pack, passo, total, d_out);
  k_stage<<<512, 256, 0, stream>>>(X, W, flag, XT, Xb, Wb);
  k_w2   <<<NN/4, 256, 0, stream>>>(W, Wb, flag, w2);
  k_score<<<dim3(16, 32), 256, 0, stream>>>(X, W, Xb, Wb, flag, w2, pack);
  k_update<<<NN/16, 512, 0, stream>>>(XT, W, pack, flag, passo, total, d_out);
}

// Round 3
// 38.837 us; speedup vs baseline: 2.9466x; 1.4255x over previous
//
#include <hip/hip_runtime.h>
#include <hip/hip_bf16.h>

typedef unsigned int u32;
typedef unsigned short u16;
typedef unsigned long long u64;

#define BATCH 256
#define NN 4096
#define DIM 512

using short8 = __attribute__((ext_vector_type(8))) short;
using f32x4  = __attribute__((ext_vector_type(4))) float;

__device__ inline float b2f(u16 u){ u32 i = ((u32)u)<<16; float f; __builtin_memcpy(&f,&i,4); return f; }
__device__ inline u16 f2b(float v){ __hip_bfloat16 h = __float2bfloat16(v); u16 r; __builtin_memcpy(&r,&h,2); return r; }

__device__ inline float ldv(const void* p, size_t i, int isbf){
  return isbf ? b2f(((const u16*)p)[i]) : ((const float*)p)[i];
}
__device__ inline void stv(void* p, size_t i, float v, int isbf){
  if (isbf) ((__hip_bfloat16*)p)[i] = __float2bfloat16(v);
  else ((float*)p)[i] = v;
}

// Per-block dtype sniff (reads X[0..63] words, L2-resident) -> no cross-kernel dep.
__device__ inline int sniff(const void* X, int t, int* sh){
  if (t < 64){
    u32 v = ((const u32*)X)[t];
    u16 lo = (u16)(v & 0xffffu);
    int e = (lo >> 7) & 0xff;
    int sane = ((lo & 0x7fffu) == 0) || (e >= 110 && e <= 132);
    u64 m = __ballot(sane);
    if (t == 0) *sh = (__popcll(m) >= 32) ? 1 : 0;
  }
  __syncthreads();
  return *sh;
}

// KA: fused prep. Blocks 0..511: XT column build (+Xb convert).
//     Blocks 512..1023: w2 for 8 W-rows (+Wb convert); block 512 inits pack+scalars.
__global__ __launch_bounds__(256) void k_prep(const void* X, const void* W,
    u64* pack, float* w2, u16* XT, u16* Xb, u16* Wb,
    const int* passo, const int* total, void* out){
  __shared__ int sflag;
  int t = threadIdx.x;
  int isbf = sniff(X, t, &sflag);
  int blk = blockIdx.x;
  if (blk < 512){
    int d = blk;
    float v = ldv(X, (size_t)t*DIM + d, isbf);
    XT[(size_t)d*BATCH + t] = f2b(v);
    if (!isbf){
      size_t i = (size_t)d*256 + t;     // 512*256 = |X|
      Xb[i] = f2b(((const float*)X)[i]);
    }
  } else {
    int j = blk - 512;                  // 0..511, rows n0..n0+7
    int n0 = j*8;
    int wv = t>>6, lane = t&63;
    #pragma unroll
    for (int rr=0; rr<2; ++rr){
      int n = n0 + wv*2 + rr;
      float xv[8]; float s = 0.f;
      if (isbf){
        short8 x = *(const short8*)((const u16*)W + (size_t)n*DIM + lane*8);
        #pragma unroll
        for (int q=0;q<8;q++) xv[q] = b2f((u16)x[q]);
      } else {
        #pragma unroll
        for (int q=0;q<8;q++) xv[q] = ((const float*)W)[(size_t)n*DIM + lane*8 + q];
      }
      #pragma unroll
      for (int q=0;q<8;q++) s += xv[q]*xv[q];
      #pragma unroll
      for (int off=32; off; off>>=1) s += __shfl_down(s, off);
      if (lane == 0) w2[n] = s;
      if (!isbf){
        #pragma unroll
        for (int q=0;q<8;q++) Wb[(size_t)n*DIM + lane*8 + q] = f2b(xv[q]);
      }
    }
    if (j == 0){
      pack[t] = ~0ull;
      if (t == 0){
        float decay = expf(-(float)passo[0]/(float)total[0]);
        stv(out, (size_t)NN*DIM,     0.5f*decay, isbf);
        stv(out, (size_t)NN*DIM + 1, 32.f*decay, isbf);
      }
    }
  }
}

// KB: MFMA score + fused argmin. Wave tile 32b x 32n (2x2 fragments).
// 256 blocks (1/CU): 8 b-tiles x 32 n-chunks, XCD-grouped so the 8 blocks
// sharing an n-chunk's W rows land on one XCD's L2.
__global__ __launch_bounds__(256) void k_score(const void* X, const void* W,
    const u16* Xws, const u16* Wws, const float* w2, u64* pack){
  __shared__ int sflag;
  __shared__ float sval[4][32];
  __shared__ int   sidx[4][32];
  int t = threadIdx.x;
  int isbf = sniff(X, t, &sflag);
  const u16* Xb = isbf ? (const u16*)X : Xws;
  const u16* Wb = isbf ? (const u16*)W : Wws;
  int wv = t>>6, l = t&63;
  int lr = l&15, lg = l>>4;

  int id = blockIdx.x;                 // bijective XCD-aware decode
  int xcd = id & 7, sub = id >> 3;     // 8 XCDs x 32 blocks
  int ny = xcd*4 + (sub>>3);           // n-chunk 0..31 (4 per XCD)
  int bx = sub & 7;                    // b-tile 0..7
  int b0 = bx*32;
  int n0 = ny*128 + wv*32;

  const u16* xp0 = Xb + (size_t)(b0 + lr)*DIM + lg*8;
  const u16* xp1 = xp0 + (size_t)16*DIM;
  const u16* wp0 = Wb + (size_t)(n0 + lr)*DIM + lg*8;
  const u16* wp1 = wp0 + (size_t)16*DIM;

  f32x4 acc00 = {0,0,0,0}, acc01 = {0,0,0,0}, acc10 = {0,0,0,0}, acc11 = {0,0,0,0};
  #pragma unroll
  for (int ks=0; ks<16; ++ks){
    short8 a0 = *(const short8*)(xp0 + ks*32);
    short8 a1 = *(const short8*)(xp1 + ks*32);
    short8 w0 = *(const short8*)(wp0 + ks*32);
    short8 w1 = *(const short8*)(wp1 + ks*32);
    acc00 = __builtin_amdgcn_mfma_f32_16x16x32_bf16(a0, w0, acc00, 0,0,0);
    acc01 = __builtin_amdgcn_mfma_f32_16x16x32_bf16(a0, w1, acc01, 0,0,0);
    acc10 = __builtin_amdgcn_mfma_f32_16x16x32_bf16(a1, w0, acc10, 0,0,0);
    acc11 = __builtin_amdgcn_mfma_f32_16x16x32_bf16(a1, w1, acc11, 0,0,0);
  }

  float w20 = w2[n0 + lr];
  float w21 = w2[n0 + 16 + lr];
  #pragma unroll
  for (int bb=0; bb<2; ++bb){
    #pragma unroll
    for (int r=0;r<4;++r){
      float s0 = w20 - 2.f*(bb ? acc10[r] : acc00[r]);
      float s1 = w21 - 2.f*(bb ? acc11[r] : acc01[r]);
      float bv; int bi;
      if (s0 <= s1){ bv = s0; bi = n0 + lr; } else { bv = s1; bi = n0 + 16 + lr; }
      #pragma unroll
      for (int m=1; m<16; m<<=1){
        float ov = __shfl_xor(bv, m);
        int   oi = __shfl_xor(bi, m);
        if (ov < bv || (ov == bv && oi < bi)){ bv = ov; bi = oi; }
      }
      if (lr == 0){ int bl = bb*16 + lg*4 + r; sval[wv][bl] = bv; sidx[wv][bl] = bi; }
    }
  }
  __syncthreads();
  if (t < 32){                          // cross-wave combine -> 32 atomics/block
    float bv = sval[0][t]; int bi = sidx[0][t];
    #pragma unroll
    for (int w4=1; w4<4; ++w4){
      float ov = sval[w4][t]; int oi = sidx[w4][t];
      if (ov < bv || (ov == bv && oi < bi)){ bv = ov; bi = oi; }
    }
    u32 sb = __float_as_uint(bv);
    sb = (sb & 0x80000000u) ? ~sb : (sb | 0x80000000u);
    atomicMin(pack + b0 + t, ((u64)sb << 32) | (u32)bi);
  }
}

// KC: h tile in LDS -> MFMA hX = h @ XT -> fused SOM update.
// Block: 16 n rows, 512 threads = 8 waves, wave wv covers d in [wv*64, wv*64+64).
__global__ __launch_bounds__(512) void k_update(const void* X, const u16* XT, const void* W,
    const u64* pack, const int* passo, const int* total, void* out){
  __shared__ int sflag;
  __shared__ u16 hT[16][264];
  __shared__ float hpart[8][8];
  __shared__ float hs[16];
  int t = threadIdx.x;
  int isbf = sniff(X, t, &sflag);
  int wv = t>>6, l = t&63;
  int n0 = blockIdx.x * 16;

  float decay = expf(-(float)passo[0] / (float)total[0]);
  float taxa = 0.5f*decay, sigma = 32.f*decay;
  float inv2s2 = 1.f/(2.f*sigma*sigma);

  { // h fill: thread handles b = t&255, rows (t>>8)*8 .. +8
    int b = t & 255;
    int rbase = (t >> 8) * 8;
    int m = (int)(u32)(pack[b] & 0xffffffffu);
    int mx = m & 63, my = m >> 6;
    float hv[8];
    #pragma unroll
    for (int i=0;i<8;++i){
      int n = n0 + rbase + i;
      int dx = (n & 63) - mx;
      int dy = (n >> 6) - my;
      float h = expf(-(float)(dx*dx + dy*dy) * inv2s2);
      hv[i] = h;
      hT[rbase + i][b] = f2b(h);
    }
    #pragma unroll
    for (int i=0;i<8;++i){
      float s = hv[i];
      #pragma unroll
      for (int off=32; off; off>>=1) s += __shfl_down(s, off);
      if (l == 0) hpart[wv][i] = s;
    }
  }
  __syncthreads();
  if (t < 16){
    int g = (t >> 3) * 4;
    hs[t] = hpart[g][t&7] + hpart[g+1][t&7] + hpart[g+2][t&7] + hpart[g+3][t&7];
  }
  __syncthreads();

  int lr = l & 15, lg = l >> 4;
  int d0 = wv * 64;
  f32x4 acc[4];
  #pragma unroll
  for (int f=0;f<4;++f) acc[f] = (f32x4){0.f,0.f,0.f,0.f};

  #pragma unroll
  for (int ks=0; ks<8; ++ks){
    short8 a = *(const short8*)(&hT[lr][ks*32 + lg*8]);
    #pragma unroll
    for (int f=0; f<4; ++f){
      short8 bfr = *(const short8*)(XT + (size_t)(d0 + f*16 + lr)*BATCH + ks*32 + lg*8);
      acc[f] = __builtin_amdgcn_mfma_f32_16x16x32_bf16(a, bfr, acc[f], 0,0,0);
    }
  }

  float cc = taxa / (float)BATCH;
  #pragma unroll
  for (int r=0;r<4;++r){
    int n = n0 + lg*4 + r;
    float hsv = hs[lg*4 + r];
    #pragma unroll
    for (int f=0;f<4;++f){
      size_t gi = (size_t)n*DIM + d0 + f*16 + lr;
      float wv_ = ldv(W, gi, isbf);
      float o = wv_ + cc*(acc[f][r] - hsv*wv_);
      stv(out, gi, o, isbf);
    }
  }
}

extern "C" void kernel_launch(void* const* d_in, const int* in_sizes, int n_in,
                              void* d_out, int out_size, void* d_ws, size_t ws_size,
                              hipStream_t stream) {
  const void* X = d_in[0];      // (256, 512)
  const void* W = d_in[1];      // (4096, 512)
  // d_in[2] = localizacoes — recomputed on device as (n%64, n/64)
  const int* passo = (const int*)d_in[3];
  const int* total = (const int*)d_in[4];

  char* ws = (char*)d_ws;
  u64* pack = (u64*)(ws + 256);                 // 256 * 8
  float* w2 = (float*)(ws + 2304);              // 4096 * 4
  u16* XT   = (u16*)(ws + 18688);               // 512*256*2
  u16* Xb   = (u16*)(ws + 280832);              // f32 fallback
  u16* Wb   = (u16*)(ws + 542976);              // f32 fallback (4 MiB)

  k_prep  <<<1024, 256, 0, stream>>>(X, W, pack, w2, XT, Xb, Wb, passo, total, d_out);
  k_score <<<256, 256, 0, stream>>>(X, W, Xb, Wb, w2, pack);
  k_update<<<NN/16, 512, 0, stream>>>(X, XT, W, pack, passo, total, d_out);
}